// Round 5
// baseline (86.634 us; speedup 1.0000x reference)
//
#include <hip/hip_runtime.h>

// DNM dendritic layer: out[b,o] = max(0, 0.25*S - 0.05),
//   S = sum_{m,i} relu(fma(x[b,i], W[o,m,i], -q[o,m,i]))
// B=512, OUT=128, M=8, IN=512, fp32.
// Pipe floors all ~5us (VALU 5.1, LDS 5.1, L2 ~4). R1/R4 showed an invariant
// ~28us stall component -> exposed x-load latency + staging serialization.
// R5: double-buffered x prefetch across (pass,chunk) iterations + 2 passes
// per block (one staging+barrier per 64 b's). R2/R3 lessons kept: no VGPR
// cap, unroll 1 on the outer loop, pk math throughout.

#define OUTN 128
#define MM   8
#define INN  512

typedef float f4 __attribute__((ext_vector_type(4)));

// Block: 256 threads = 4 waves, one o, 32 b's per pass, 2 passes (64 b's).
// Grid: 128 o * 8 b-groups = 1024 blocks. LDS 32 KB.
__global__ __launch_bounds__(256) void dnm_kernel(
    const float* __restrict__ x,   // [B, IN]
    const float* __restrict__ W,   // [OUT, M, IN]
    const float* __restrict__ q,   // [OUT, M, IN]
    float* __restrict__ out)       // [B, OUT]
{
    __shared__ float lds_w[MM * INN];
    __shared__ float lds_q[MM * INN];

    const int tid  = threadIdx.x;
    const int o    = blockIdx.x >> 3;
    const int bgrp = blockIdx.x & 7;
    const int wave = tid >> 6;
    const int lane = tid & 63;

    // Stage W[o,:,:] and q[o,:,:] (32 KB) into LDS, coalesced float4.
    {
        const f4* Wg = (const f4*)(W + (size_t)o * MM * INN);
        const f4* qg = (const f4*)(q + (size_t)o * MM * INN);
        f4* lw = (f4*)lds_w;
        f4* lq = (f4*)lds_q;
        #pragma unroll
        for (int j = 0; j < (MM * INN / 4); j += 256) {
            lw[j + tid] = Wg[j + tid];
            lq[j + tid] = qg[j + tid];
        }
    }

    // Preload x for iteration 0 (pass 0, chunk 0) BEFORE the barrier —
    // overlaps with other waves' staging.
    f4 xcur[8], xnxt[8];
    {
        const int b0 = bgrp * 64 + wave * 8;
        const int i  = lane * 4;
        #pragma unroll
        for (int b = 0; b < 8; ++b)
            xcur[b] = *(const f4*)(x + (size_t)(b0 + b) * INN + i);
    }

    __syncthreads();

    f4 acc[8];
    #pragma unroll
    for (int b = 0; b < 8; ++b) acc[b] = (f4)0.0f;

    // Flat iteration: it = pass*2 + chunk. pass selects 32 b's, chunk selects
    // 256 i's. unroll 1: keep exactly one prefetch depth live (R3 lesson).
    #pragma unroll 1
    for (int it = 0; it < 4; ++it) {
        const int pass  = it >> 1;
        const int chunk = it & 1;
        const int i     = chunk * 256 + lane * 4;

        // Prefetch next iteration's x while computing this one. The vmcnt
        // wait lands at the xcur=xnxt copy AFTER 384 pk-ops of compute.
        if (it < 3) {
            const int itn = it + 1;
            const int b0n = bgrp * 64 + (itn >> 1) * 32 + wave * 8;
            const int in_ = (itn & 1) * 256 + lane * 4;
            #pragma unroll
            for (int b = 0; b < 8; ++b)
                xnxt[b] = *(const f4*)(x + (size_t)(b0n + b) * INN + in_);
        }

        #pragma unroll
        for (int m = 0; m < MM; ++m) {
            const f4 w4 = *(const f4*)(lds_w + m * INN + i);
            const f4 q4 = *(const f4*)(lds_q + m * INN + i);
            #pragma unroll
            for (int b = 0; b < 8; ++b) {
                // 2x v_pk_fma_f32 + 2x v_pk_max_f32 + 2x v_pk_add_f32
                f4 t = __builtin_elementwise_fma(xcur[b], w4, -q4);
                t = __builtin_elementwise_max(t, (f4)0.0f);
                acc[b] += t;
            }
        }

        // End of a pass (chunk==1): reduce + write these 32 b's, reset acc.
        if (chunk == 1) {
            const int b0 = bgrp * 64 + pass * 32 + wave * 8;
            #pragma unroll
            for (int b = 0; b < 8; ++b) {
                float v = (acc[b].x + acc[b].y) + (acc[b].z + acc[b].w);
                v += __shfl_xor(v, 1, 64);
                v += __shfl_xor(v, 2, 64);
                v += __shfl_xor(v, 4, 64);
                v += __shfl_xor(v, 8, 64);
                v += __shfl_xor(v, 16, 64);
                v += __shfl_xor(v, 32, 64);
                if (lane == b) {
                    float r = 0.25f * v - 0.05f;   // K*K*S - K*QS
                    out[(size_t)(b0 + b) * OUTN + o] = fmaxf(r, 0.0f);
                }
                acc[b] = (f4)0.0f;
            }
        }

        // Rotate the double buffer (32 v_movs; ~4% of VALU issue).
        #pragma unroll
        for (int b = 0; b < 8; ++b) xcur[b] = xnxt[b];
    }
}

extern "C" void kernel_launch(void* const* d_in, const int* in_sizes, int n_in,
                              void* d_out, int out_size, void* d_ws, size_t ws_size,
                              hipStream_t stream) {
    const float* x = (const float*)d_in[0];
    const float* W = (const float*)d_in[1];
    const float* q = (const float*)d_in[2];
    float* out = (float*)d_out;
    dim3 grid(OUTN * 8);   // 128 o * 8 b-groups = 1024 blocks
    dim3 block(256);
    dnm_kernel<<<grid, block, 0, stream>>>(x, W, q, out);
}